// Round 13
// baseline (387.734 us; speedup 1.0000x reference)
//
#include <hip/hip_runtime.h>
#include <hip/hip_bf16.h>
#include <stdint.h>

// MultiHeadDiffAttention — R13. R12 showed barriers/conflicts NOT the stall;
// accounting points to (a) 32-line gather staging loads (K rows / vvT rows are
// 4KB apart) and (b) only 2 waves/SIMD. Fixes: kT[(b,s,h)][t][d] layout for K
// (GEMM k-half epilogue) -> contiguous tile staging; V staging re-assigned
// along t (full-line reads); block 256->512 (8 waves, 128 q-rows, grid 512,
// 2 blocks/CU resident = 4 waves/SIMD); L-sum shfl hoisted out of the loop.
// B=2, T=2048, C=1024, H=16, HS=64.

#define T_SEQ 2048

typedef unsigned short u16;
typedef __attribute__((ext_vector_type(8))) short short8;
typedef __attribute__((ext_vector_type(4))) float f32x4;
typedef __attribute__((ext_vector_type(16))) float f32x16;

#define LAMBDA_INIT 0.35550906759096926f
#define ONE_MINUS_LI 0.6444909324090307f
#define SM_SCALE 0.125f
#define LOG2E 1.44269504f

__device__ __forceinline__ u16 f2bf(float f) {
  uint32_t u = __float_as_uint(f);
  return (u16)((u + 0x7FFFu + ((u >> 16) & 1u)) >> 16);
}
__device__ __forceinline__ float b2f(u16 u) {
  return __uint_as_float(((uint32_t)u) << 16);
}
__device__ __forceinline__ short8 ld8(const u16* p) {
  return *reinterpret_cast<const short8*>(p);
}
__device__ __forceinline__ void st8(u16* p, short8 v) {
  *reinterpret_cast<short8*>(p) = v;
}
__device__ __forceinline__ f32x4 mfma16(short8 a, short8 b, f32x4 c) {
  return __builtin_amdgcn_mfma_f32_16x16x32_bf16(a, b, c, 0, 0, 0);
}
__device__ __forceinline__ f32x16 mfma32(short8 a, short8 b, f32x16 c) {
  return __builtin_amdgcn_mfma_f32_32x32x16_bf16(a, b, c, 0, 0, 0);
}
__device__ __forceinline__ uint32_t cvtpk(float lo, float hi_) {
  uint32_t r;
  asm("v_cvt_pk_bf16_f32 %0, %1, %2" : "=v"(r) : "v"(lo), "v"(hi_));
  return r;
}

// ---------------- elementwise f32 -> bf16 ----------------
__global__ __launch_bounds__(256) void cvt_bf16(const float* __restrict__ in,
                                                u16* __restrict__ out, int n) {
  int i = (blockIdx.x * 256 + threadIdx.x) * 4;
  if (i >= n) return;
  float4 f = *reinterpret_cast<const float4*>(in + i);
  union { u16 u[4]; uint2 v; } pk;
  pk.u[0] = f2bf(f.x); pk.u[1] = f2bf(f.y); pk.u[2] = f2bf(f.z); pk.u[3] = f2bf(f.w);
  *reinterpret_cast<uint2*>(out + i) = pk.v;
}

// ------------- transpose + convert: W[K][N] f32 -> WT[N][K] bf16 -------------
__global__ __launch_bounds__(256) void tcvt(const float* __restrict__ W,
                                            u16* __restrict__ WT,
                                            int K, int N, int outRowOff) {
  __shared__ float tile[32][33];
  int n0 = blockIdx.x * 32, k0 = blockIdx.y * 32;
  int tx = threadIdx.x & 31, ty = threadIdx.x >> 5;  // ty 0..7
#pragma unroll
  for (int p = 0; p < 4; ++p)
    tile[ty + 8 * p][tx] = W[(size_t)(k0 + ty + 8 * p) * N + n0 + tx];
  __syncthreads();
#pragma unroll
  for (int p = 0; p < 4; ++p)
    WT[(size_t)(outRowOff + n0 + ty + 8 * p) * K + k0 + tx] = f2bf(tile[tx][ty + 8 * p]);
}

// ---------------- concat two 1024-float biases ----------------
__global__ __launch_bounds__(256) void bias_concat(const float* __restrict__ b1,
                                                   const float* __restrict__ b2,
                                                   float* __restrict__ out) {
  int i = blockIdx.x * 256 + threadIdx.x;  // 0..2047
  out[i] = (i < 1024) ? b1[i] : b2[i - 1024];
}

// ---------------- GEMM: C[M][N] = A[M][K] @ BT[N][K]^T + bias ----------------
// m97 geometry: 128x128 tile, BK=64, 4 waves, global_load_lds width 16.
// EPI 1: bf16 vvT ((b*2048+col)*2048 + t).  EPI 2: f32 [M][N].
// EPI 4 (fused q|k): rows<4096 -> bf16 [M][2048] q1q2; rows>=4096 -> kT layout
//   kT[((b*2+stream)*16+h)][t][d] at Cv+8388608 (stream=col>>10, h=(col>>6)&15).
#define BM 128
#define BN 128
#define BK 64

template <int EPI, bool QK>
__global__ __launch_bounds__(256) void gemm_bt(const u16* __restrict__ A,
                                               const u16* __restrict__ BT,
                                               const float* __restrict__ bias,
                                               void* __restrict__ Cv,
                                               int M, int N, int K) {
  __shared__ __align__(16) u16 As[BM * BK];
  __shared__ __align__(16) u16 Bs[BN * BK];
  int t = threadIdx.x;
  int w = t >> 6, l = t & 63;
  int g = l >> 4, c16 = l & 15;
  int wr = w >> 1, wc = w & 1;
  size_t gm = (size_t)blockIdx.y * BM, gn = (size_t)blockIdx.x * BN;
  if (QK && gm >= 4096) {
    BT += (size_t)2048 * 1024;  // Wk12T follows Wq12T
    bias += 2048;               // biask follows biasq
  }

  f32x4 acc[4][4] = {};

  int srow = l >> 3;       // 0..7 (8 lanes per row, 8 elems each)
  int scol = (l & 7) * 8;  // 0..56
  const u16* Ag = A + (gm + w * 32 + srow) * (size_t)K + scol;
  const u16* Bg = BT + (gn + w * 32 + srow) * (size_t)K + scol;

  for (int kt = 0; kt < K; kt += BK) {
    __syncthreads();
#pragma unroll
    for (int c = 0; c < 4; ++c) {
      __builtin_amdgcn_global_load_lds(
          (const __attribute__((address_space(1))) void*)(Ag + (size_t)(c * 8) * K + kt),
          (__attribute__((address_space(3))) void*)&As[(w * 32 + c * 8) * BK], 16, 0, 0);
      __builtin_amdgcn_global_load_lds(
          (const __attribute__((address_space(1))) void*)(Bg + (size_t)(c * 8) * K + kt),
          (__attribute__((address_space(3))) void*)&Bs[(w * 32 + c * 8) * BK], 16, 0, 0);
    }
    __syncthreads();
#pragma unroll
    for (int kk = 0; kk < 2; ++kk) {
      short8 af[4], bf[4];
#pragma unroll
      for (int m = 0; m < 4; ++m)
        af[m] = *reinterpret_cast<const short8*>(
            &As[(wr * 64 + m * 16 + c16) * BK + kk * 32 + g * 8]);
#pragma unroll
      for (int n = 0; n < 4; ++n)
        bf[n] = *reinterpret_cast<const short8*>(
            &Bs[(wc * 64 + n * 16 + c16) * BK + kk * 32 + g * 8]);
#pragma unroll
      for (int m = 0; m < 4; ++m)
#pragma unroll
        for (int n = 0; n < 4; ++n)
          acc[m][n] = mfma16(af[m], bf[n], acc[m][n]);
    }
  }

#pragma unroll
  for (int m = 0; m < 4; ++m)
#pragma unroll
    for (int n = 0; n < 4; ++n) {
      int row0 = (int)gm + wr * 64 + m * 16 + g * 4;
      int col = (int)gn + wc * 64 + n * 16 + c16;
      float bz = bias[col];
      if (EPI == 1) {
        u16* C = (u16*)Cv;
        int bb = row0 >> 11, tt = row0 & 2047;
        union { u16 u[4]; uint2 v; } pk;
#pragma unroll
        for (int r = 0; r < 4; ++r) pk.u[r] = f2bf(acc[m][n][r] + bz);
        *reinterpret_cast<uint2*>(&C[((size_t)(bb * 2048 + col)) * 2048 + tt]) = pk.v;
      } else if (EPI == 2) {
        float* C = (float*)Cv;
#pragma unroll
        for (int r = 0; r < 4; ++r)
          C[(size_t)(row0 + r) * N + col] = acc[m][n][r] + bz;
      } else {  // EPI == 4: fused q|k
        u16* C = (u16*)Cv;
        if (row0 < 4096) {
#pragma unroll
          for (int r = 0; r < 4; ++r)
            C[(size_t)(row0 + r) * N + col] = f2bf(acc[m][n][r] + bz);
        } else {
          int t0 = row0 - 4096;
          int bb = t0 >> 11, tt = t0 & 2047;
          int str = col >> 10, hh = (col >> 6) & 15, dd = col & 63;
          u16* KT = C + 8388608;
          size_t base = (((size_t)(bb * 2 + str) * 16 + hh) * 2048 + tt) * (size_t)64 + dd;
#pragma unroll
          for (int r = 0; r < 4; ++r) KT[base + (size_t)r * 64] = f2bf(acc[m][n][r] + bz);
        }
      }
    }
}

// ---------------- differential flash attention + fused LN (32x32 swapped) ----
// grid 512 (1D, XCD-swizzled), block 512 = 8 waves = 4 pairs.
// Pair p covers q-rows [xblk*128 + p*32, +32); wave stream s handles stream s+1.
// 64-key staged tiles, 2-barrier R8-proven staging, fully coalesced sources.
#define KROW 72   // K/V LDS row: 64 elems + 8 pad (144B)
#define YROW 72
__global__ __launch_bounds__(512, 4) void diffattn(
    const u16* __restrict__ q1q2, const u16* __restrict__ kT,
    const u16* __restrict__ vvT, const int* __restrict__ mask,
    const float* __restrict__ lq1, const float* __restrict__ lk1,
    const float* __restrict__ lq2, const float* __restrict__ lk2,
    const float* __restrict__ lnw, const float* __restrict__ lnb,
    u16* __restrict__ yout) {
  // Ks [128 rows = stream*64+key][KROW] = 9216 ; Vs [128 d-rows][KROW] = 9216
  __shared__ __align__(16) u16 smem[18432];
  u16* Ksm = smem;
  u16* Vsm = smem + 9216;
  u16* Ysm = smem;  // epilogue overlay: [256 rows][YROW] = 18432

  int tid = threadIdx.x;           // 0..511
  int w = tid >> 6, l = tid & 63;
  int q = l & 31, hi = l >> 5;
  int pair = w >> 1, stream = w & 1;  // pair 0..3

  // XCD swizzle: same-(b,h) q-blocks land on one XCD -> K/V L2-local (4MB/XCD)
  int id = blockIdx.x;             // 0..511
  int j = id & 7, rest = id >> 3;  // rest 0..63
  int xblk = rest & 15, ygrp = rest >> 4;
  int bh = ygrp * 8 + j;
  int b = bh >> 4, h = bh & 15;
  int qr0 = xblk * 128 + pair * 32;

  // lambda
  float lm1 = lq1[h * 64 + l] * lk1[h * 64 + l];
  float lm2 = lq2[h * 64 + l] * lk2[h * 64 + l];
#pragma unroll
  for (int o = 32; o; o >>= 1) {
    lm1 += __shfl_xor(lm1, o);
    lm2 += __shfl_xor(lm2, o);
  }
  float lam = __expf(lm1) - __expf(lm2) + LAMBDA_INIT;

  int soff = stream * 1024;
  const u16* qrow = q1q2 + (size_t)(b * T_SEQ + qr0 + q) * 2048 + h * 64 + soff + hi * 8;
  short8 qf[4];
#pragma unroll
  for (int c = 0; c < 4; ++c) qf[c] = ld8(qrow + c * 16);

  // softmax in log2 domain; mask folds into scale (0 -> uniform softmax)
  float scale = (mask[b * T_SEQ + qr0 + q] == 0) ? 0.f : (SM_SCALE * LOG2E);

  float M = -INFINITY, Lp = 0.f;
  f32x16 acc[4] = {};

  // ---- coalesced staging assignments (512 threads, 4 ld8/thread) ----
  // K: kT tile is contiguous 8KB per stream; unit u=stream: elem = tid*8
  int skey = tid >> 3, sd = (tid & 7) * 8;
  const u16* srcK0 = kT + (((size_t)(b * 2 + 0) * 16 + h) * 2048 + skey) * 64 + sd;
  const u16* srcK1 = kT + (((size_t)(b * 2 + 1) * 16 + h) * 2048 + skey) * 64 + sd;
  u16* dstK0 = &Ksm[skey * KROW + sd];
  u16* dstK1 = &Ksm[(64 + skey) * KROW + sd];
  // V: vvT rows are t-contiguous; 8 lanes cover one d-row's 64 keys (1 line)
  int vd0 = tid >> 3, tcol = (tid & 7) * 8;
  const u16* srcV0 = vvT + ((size_t)(b * 16 + h) * 128 + vd0) * 2048 + tcol;
  const u16* srcV1 = vvT + ((size_t)(b * 16 + h) * 128 + 64 + vd0) * 2048 + tcol;
  u16* dstV0 = &Vsm[vd0 * KROW + tcol];
  u16* dstV1 = &Vsm[(64 + vd0) * KROW + tcol];

  short8 kp0 = ld8(srcK0), kp1 = ld8(srcK1);
  short8 vp0 = ld8(srcV0), vp1 = ld8(srcV1);

  for (int kt = 0; kt < T_SEQ; kt += 64) {
    __syncthreads();  // previous tile's reads complete
    st8(dstK0, kp0); st8(dstK1, kp1);
    st8(dstV0, vp0); st8(dstV1, vp1);
    __syncthreads();  // tile staged
    if (kt + 64 < T_SEQ) {  // prefetch next tile (consumed NEXT iter)
      size_t ko = (size_t)(kt + 64) * 64;
      kp0 = ld8(srcK0 + ko); kp1 = ld8(srcK1 + ko);
      vp0 = ld8(srcV0 + kt + 64); vp1 = ld8(srcV1 + kt + 64);
    }

#pragma unroll
    for (int st = 0; st < 2; ++st) {
      const u16* kbase = &Ksm[(stream * 64 + st * 32 + q) * KROW + hi * 8];
      short8 kf[4];
#pragma unroll
      for (int c = 0; c < 4; ++c) kf[c] = ld8(kbase + c * 16);

      f32x16 s = {};
#pragma unroll
      for (int c = 0; c < 4; ++c) s = mfma32(kf[c], qf[c], s);

      // tile max: max3-fusable tree + cross-half
      float m0 = fmaxf(fmaxf(s[0], s[1]), s[2]);
      float m1 = fmaxf(fmaxf(s[3], s[4]), s[5]);
      float m2 = fmaxf(fmaxf(s[6], s[7]), s[8]);
      float m3 = fmaxf(fmaxf(s[9], s[10]), s[11]);
      float m4 = fmaxf(fmaxf(s[12], s[13]), s[14]);
      float ma = fmaxf(fmaxf(m0, m1), m2);
      float mb = fmaxf(fmaxf(m3, m4), s[15]);
      float rm = fmaxf(ma, mb);
      rm = fmaxf(rm, __shfl_xor(rm, 32));
      float tm = rm * scale;

      // defer-max (log2 units: 11.5 ~ e^8); M synced across halves
      if (!__all(tm - M <= 11.5f)) {
        float Mn = fmaxf(M, tm);
        float a = exp2f(M - Mn);
        Lp *= a;
#pragma unroll
        for (int d = 0; d < 4; ++d) acc[d] *= a;
        M = Mn;
      }

      // p = exp2(s*scale - M); lane-local partial sum (combine once at end)
      float p[16];
#pragma unroll
      for (int r = 0; r < 16; ++r) p[r] = exp2f(__builtin_fmaf(s[r], scale, -M));
      float s8[8], s4[4];
#pragma unroll
      for (int i = 0; i < 8; ++i) s8[i] = p[i] + p[i + 8];
#pragma unroll
      for (int i = 0; i < 4; ++i) s4[i] = s8[i] + s8[i + 4];
      Lp += (s4[0] + s4[1]) + (s4[2] + s4[3]);

      // P^T B-frags in-register
      uint32_t a1 = cvtpk(p[0], p[1]), a2 = cvtpk(p[2], p[3]);
      uint32_t b1 = cvtpk(p[4], p[5]), b2 = cvtpk(p[6], p[7]);
      uint32_t c1 = cvtpk(p[8], p[9]), c2 = cvtpk(p[10], p[11]);
      uint32_t d1 = cvtpk(p[12], p[13]), d2 = cvtpk(p[14], p[15]);
      uint32_t sa1 = (uint32_t)__shfl_xor((int)a1, 32), sa2 = (uint32_t)__shfl_xor((int)a2, 32);
      uint32_t sb1 = (uint32_t)__shfl_xor((int)b1, 32), sb2 = (uint32_t)__shfl_xor((int)b2, 32);
      uint32_t sc1 = (uint32_t)__shfl_xor((int)c1, 32), sc2 = (uint32_t)__shfl_xor((int)c2, 32);
      uint32_t sd1 = (uint32_t)__shfl_xor((int)d1, 32), sd2 = (uint32_t)__shfl_xor((int)d2, 32);
      union { uint32_t u[4]; short8 s8v; } pu0, pu1;
      pu0.u[0] = hi ? sb1 : a1;  pu0.u[1] = hi ? sb2 : a2;
      pu0.u[2] = hi ? b1 : sa1;  pu0.u[3] = hi ? b2 : sa2;
      pu1.u[0] = hi ? sd1 : c1;  pu1.u[1] = hi ? sd2 : c2;
      pu1.u[2] = hi ? d1 : sc1;  pu1.u[3] = hi ? d2 : sc2;
      short8 pf0 = pu0.s8v, pf1 = pu1.s8v;

#pragma unroll
      for (int d = 0; d < 4; ++d) {
        const u16* vb0 = &Vsm[(d * 32 + q) * KROW + st * 32 + hi * 8];
        short8 vf0 = ld8(vb0);
        short8 vf1 = ld8(vb0 + 16);
        acc[d] = mfma32(vf0, pf0, acc[d]);
        acc[d] = mfma32(vf1, pf1, acc[d]);
      }
    }
  }

  float L = Lp + __shfl_xor(Lp, 32);
  float inv = 1.f / L;
  __syncthreads();  // staging dead -> Ysm overlay safe
  if (stream == 1) {
    u16* yrow = &Ysm[(pair * 64 + l) * YROW];
#pragma unroll
    for (int d = 0; d < 4; ++d) {
      union { uint32_t u[8]; short8 v[2]; } pk;
#pragma unroll
      for (int i = 0; i < 8; ++i)
        pk.u[i] = cvtpk(acc[d][2 * i] * inv, acc[d][2 * i + 1] * inv);
      st8(yrow + d * 16, pk.v[0]);
      st8(yrow + d * 16 + 8, pk.v[1]);
    }
  }
  __syncthreads();
  if (stream == 0) {
    const u16* yrow = &Ysm[(pair * 64 + l) * YROW];
    float y[4][16];
#pragma unroll
    for (int d = 0; d < 4; ++d) {
      short8 y2a = ld8(yrow + d * 16);
      short8 y2b = ld8(yrow + d * 16 + 8);
#pragma unroll
      for (int i = 0; i < 8; ++i) {
        y[d][i] = acc[d][i] * inv - lam * b2f((u16)y2a[i]);
        y[d][8 + i] = acc[d][8 + i] * inv - lam * b2f((u16)y2b[i]);
      }
    }
    float sm = 0.f;
#pragma unroll
    for (int d = 0; d < 4; ++d)
#pragma unroll
      for (int r = 0; r < 16; ++r) sm += y[d][r];
    sm += __shfl_xor(sm, 32);
    float u = sm * (1.f / 128.f);
    float var = 0.f;
#pragma unroll
    for (int d = 0; d < 4; ++d)
#pragma unroll
      for (int r = 0; r < 16; ++r) { float dd = y[d][r] - u; var += dd * dd; }
    var += __shfl_xor(var, 32);
    float rstd = rsqrtf(var * (1.f / 128.f) + 1e-12f);

    size_t orow = (size_t)(b * T_SEQ + qr0 + q) * 2048 + h * 128;
#pragma unroll
    for (int d = 0; d < 4; ++d)
#pragma unroll
      for (int rr = 0; rr < 4; ++rr) {
        int base = d * 32 + 8 * rr + 4 * hi;
        union { u16 u[4]; uint2 v; } o;
#pragma unroll
        for (int i = 0; i < 4; ++i) {
          float yv = (lnw[base + i] * ((y[d][rr * 4 + i] - u) * rstd) + lnb[base + i]) *
                     ONE_MINUS_LI;
          o.u[i] = f2bf(yv);
        }
        *reinterpret_cast<uint2*>(&yout[orow + base]) = o.v;
      }
  }
}

// ---------------- host ----------------
extern "C" void kernel_launch(void* const* d_in, const int* in_sizes, int n_in,
                              void* d_out, int out_size, void* d_ws, size_t ws_size,
                              hipStream_t stream) {
  (void)in_sizes; (void)n_in; (void)out_size; (void)ws_size;
  const float* q   = (const float*)d_in[0];
  const float* k   = (const float*)d_in[1];
  const float* v   = (const float*)d_in[2];
  const int* maskp = (const int*)d_in[3];
  const float* Wq1 = (const float*)d_in[4];
  const float* bq1 = (const float*)d_in[5];
  const float* Wq2 = (const float*)d_in[6];
  const float* bq2 = (const float*)d_in[7];
  const float* Wk1 = (const float*)d_in[8];
  const float* bk1 = (const float*)d_in[9];
  const float* Wk2 = (const float*)d_in[10];
  const float* bk2 = (const float*)d_in[11];
  const float* Wv  = (const float*)d_in[12];
  const float* bv  = (const float*)d_in[13];
  const float* Wc  = (const float*)d_in[14];
  const float* bc  = (const float*)d_in[15];
  const float* lnw = (const float*)d_in[16];
  const float* lnb = (const float*)d_in[17];
  const float* lq1 = (const float*)d_in[18];
  const float* lk1 = (const float*)d_in[19];
  const float* lq2 = (const float*)d_in[20];
  const float* lk2 = (const float*)d_in[21];

  char* ws = (char*)d_ws;
  u16* qb     = (u16*)(ws + 0);          // rows 0..4095 ; kb continues at 4096
  u16* kb     = (u16*)(ws + 8388608);
  u16* vb     = (u16*)(ws + 16777216);
  u16* Wq12T  = (u16*)(ws + 25165824);   // Wk12T contiguous after
  u16* Wk12T  = (u16*)(ws + 29360128);
  u16* WvT    = (u16*)(ws + 33554432);
  u16* WcT    = (u16*)(ws + 37748736);
  float* biasq = (float*)(ws + 41943040);  // biask contiguous after
  float* biask = (float*)(ws + 41951232);
  u16* q1q2   = (u16*)(ws + 41959424);   // kT contiguous after (+8388608 elems)
  u16* kT     = (u16*)(ws + 58736640);
  u16* vvT    = (u16*)(ws + 75513856);
  u16* yb     = (u16*)(ws + 0);  // alias qb+kb (16MB; both dead before attention)

  const int NELEM = 2 * T_SEQ * 1024;  // 4,194,304

  cvt_bf16<<<4096, 256, 0, stream>>>(q, qb, NELEM);
  cvt_bf16<<<4096, 256, 0, stream>>>(k, kb, NELEM);
  cvt_bf16<<<4096, 256, 0, stream>>>(v, vb, NELEM);

  tcvt<<<dim3(32, 32), 256, 0, stream>>>(Wq1, Wq12T, 1024, 1024, 0);
  tcvt<<<dim3(32, 32), 256, 0, stream>>>(Wq2, Wq12T, 1024, 1024, 1024);
  tcvt<<<dim3(32, 32), 256, 0, stream>>>(Wk1, Wk12T, 1024, 1024, 0);
  tcvt<<<dim3(32, 32), 256, 0, stream>>>(Wk2, Wk12T, 1024, 1024, 1024);
  tcvt<<<dim3(64, 32), 256, 0, stream>>>(Wv, WvT, 1024, 2048, 0);
  tcvt<<<dim3(32, 64), 256, 0, stream>>>(Wc, WcT, 2048, 1024, 0);

  bias_concat<<<8, 256, 0, stream>>>(bq1, bq2, biasq);
  bias_concat<<<8, 256, 0, stream>>>(bk1, bk2, biask);

  // fused q-proj + k-proj: M=8192; q-half -> q1q2 (bf16 MN), k-half -> kT layout
  gemm_bt<4, true><<<dim3(16, 64), 256, 0, stream>>>(qb, Wq12T, biasq, q1q2,
                                                     8192, 2048, 1024);
  gemm_bt<1, false><<<dim3(16, 32), 256, 0, stream>>>(vb, WvT, bv, vvT, 4096, 2048, 1024);

  diffattn<<<512, 512, 0, stream>>>(q1q2, kT, vvT, maskp,
                                    lq1, lk1, lq2, lk2, lnw, lnb, yb);

  gemm_bt<2, false><<<dim3(8, 32), 256, 0, stream>>>(yb, WcT, bc, d_out, 4096, 1024, 2048);
}

// Round 14
// 324.946 us; speedup vs baseline: 1.1932x; 1.1932x over previous
//
#include <hip/hip_runtime.h>
#include <hip/hip_bf16.h>
#include <stdint.h>

// MultiHeadDiffAttention — R14. R13 lesson: launch_bounds w waves/EU caps
// UNIFIED VGPR+AGPR at 512/w; 64 acc-AGPRs + ~84 arch needs w<=3. (512,4)
// spilled (430MB scratch). R14 = R12's proven shape (grid 1024 x 256thr,
// bound (256,3), 2-barrier KVBLK=64 staging) + R13's coalesced staging
// (kT layout for K, V along t) + kT GEMM epilogue + hoisted L-sum.
// B=2, T=2048, C=1024, H=16, HS=64.

#define T_SEQ 2048

typedef unsigned short u16;
typedef __attribute__((ext_vector_type(8))) short short8;
typedef __attribute__((ext_vector_type(4))) float f32x4;
typedef __attribute__((ext_vector_type(16))) float f32x16;

#define LAMBDA_INIT 0.35550906759096926f
#define ONE_MINUS_LI 0.6444909324090307f
#define SM_SCALE 0.125f
#define LOG2E 1.44269504f

__device__ __forceinline__ u16 f2bf(float f) {
  uint32_t u = __float_as_uint(f);
  return (u16)((u + 0x7FFFu + ((u >> 16) & 1u)) >> 16);
}
__device__ __forceinline__ float b2f(u16 u) {
  return __uint_as_float(((uint32_t)u) << 16);
}
__device__ __forceinline__ short8 ld8(const u16* p) {
  return *reinterpret_cast<const short8*>(p);
}
__device__ __forceinline__ void st8(u16* p, short8 v) {
  *reinterpret_cast<short8*>(p) = v;
}
__device__ __forceinline__ f32x4 mfma16(short8 a, short8 b, f32x4 c) {
  return __builtin_amdgcn_mfma_f32_16x16x32_bf16(a, b, c, 0, 0, 0);
}
__device__ __forceinline__ f32x16 mfma32(short8 a, short8 b, f32x16 c) {
  return __builtin_amdgcn_mfma_f32_32x32x16_bf16(a, b, c, 0, 0, 0);
}
__device__ __forceinline__ uint32_t cvtpk(float lo, float hi_) {
  uint32_t r;
  asm("v_cvt_pk_bf16_f32 %0, %1, %2" : "=v"(r) : "v"(lo), "v"(hi_));
  return r;
}

// ---------------- elementwise f32 -> bf16 ----------------
__global__ __launch_bounds__(256) void cvt_bf16(const float* __restrict__ in,
                                                u16* __restrict__ out, int n) {
  int i = (blockIdx.x * 256 + threadIdx.x) * 4;
  if (i >= n) return;
  float4 f = *reinterpret_cast<const float4*>(in + i);
  union { u16 u[4]; uint2 v; } pk;
  pk.u[0] = f2bf(f.x); pk.u[1] = f2bf(f.y); pk.u[2] = f2bf(f.z); pk.u[3] = f2bf(f.w);
  *reinterpret_cast<uint2*>(out + i) = pk.v;
}

// ------------- transpose + convert: W[K][N] f32 -> WT[N][K] bf16 -------------
__global__ __launch_bounds__(256) void tcvt(const float* __restrict__ W,
                                            u16* __restrict__ WT,
                                            int K, int N, int outRowOff) {
  __shared__ float tile[32][33];
  int n0 = blockIdx.x * 32, k0 = blockIdx.y * 32;
  int tx = threadIdx.x & 31, ty = threadIdx.x >> 5;  // ty 0..7
#pragma unroll
  for (int p = 0; p < 4; ++p)
    tile[ty + 8 * p][tx] = W[(size_t)(k0 + ty + 8 * p) * N + n0 + tx];
  __syncthreads();
#pragma unroll
  for (int p = 0; p < 4; ++p)
    WT[(size_t)(outRowOff + n0 + ty + 8 * p) * K + k0 + tx] = f2bf(tile[tx][ty + 8 * p]);
}

// ---------------- concat two 1024-float biases ----------------
__global__ __launch_bounds__(256) void bias_concat(const float* __restrict__ b1,
                                                   const float* __restrict__ b2,
                                                   float* __restrict__ out) {
  int i = blockIdx.x * 256 + threadIdx.x;  // 0..2047
  out[i] = (i < 1024) ? b1[i] : b2[i - 1024];
}

// ---------------- GEMM: C[M][N] = A[M][K] @ BT[N][K]^T + bias ----------------
// m97 geometry: 128x128 tile, BK=64, 4 waves, global_load_lds width 16.
// EPI 1: bf16 vvT ((b*2048+col)*2048 + t).  EPI 2: f32 [M][N].
// EPI 4 (fused q|k): rows<4096 -> bf16 [M][2048] q1q2; rows>=4096 -> kT layout
//   kT[((b*2+stream)*16+h)][t][d] at Cv+8388608 (stream=col>>10, h=(col>>6)&15).
#define BM 128
#define BN 128
#define BK 64

template <int EPI, bool QK>
__global__ __launch_bounds__(256) void gemm_bt(const u16* __restrict__ A,
                                               const u16* __restrict__ BT,
                                               const float* __restrict__ bias,
                                               void* __restrict__ Cv,
                                               int M, int N, int K) {
  __shared__ __align__(16) u16 As[BM * BK];
  __shared__ __align__(16) u16 Bs[BN * BK];
  int t = threadIdx.x;
  int w = t >> 6, l = t & 63;
  int g = l >> 4, c16 = l & 15;
  int wr = w >> 1, wc = w & 1;
  size_t gm = (size_t)blockIdx.y * BM, gn = (size_t)blockIdx.x * BN;
  if (QK && gm >= 4096) {
    BT += (size_t)2048 * 1024;  // Wk12T follows Wq12T
    bias += 2048;               // biask follows biasq
  }

  f32x4 acc[4][4] = {};

  int srow = l >> 3;       // 0..7 (8 lanes per row, 8 elems each)
  int scol = (l & 7) * 8;  // 0..56
  const u16* Ag = A + (gm + w * 32 + srow) * (size_t)K + scol;
  const u16* Bg = BT + (gn + w * 32 + srow) * (size_t)K + scol;

  for (int kt = 0; kt < K; kt += BK) {
    __syncthreads();
#pragma unroll
    for (int c = 0; c < 4; ++c) {
      __builtin_amdgcn_global_load_lds(
          (const __attribute__((address_space(1))) void*)(Ag + (size_t)(c * 8) * K + kt),
          (__attribute__((address_space(3))) void*)&As[(w * 32 + c * 8) * BK], 16, 0, 0);
      __builtin_amdgcn_global_load_lds(
          (const __attribute__((address_space(1))) void*)(Bg + (size_t)(c * 8) * K + kt),
          (__attribute__((address_space(3))) void*)&Bs[(w * 32 + c * 8) * BK], 16, 0, 0);
    }
    __syncthreads();
#pragma unroll
    for (int kk = 0; kk < 2; ++kk) {
      short8 af[4], bf[4];
#pragma unroll
      for (int m = 0; m < 4; ++m)
        af[m] = *reinterpret_cast<const short8*>(
            &As[(wr * 64 + m * 16 + c16) * BK + kk * 32 + g * 8]);
#pragma unroll
      for (int n = 0; n < 4; ++n)
        bf[n] = *reinterpret_cast<const short8*>(
            &Bs[(wc * 64 + n * 16 + c16) * BK + kk * 32 + g * 8]);
#pragma unroll
      for (int m = 0; m < 4; ++m)
#pragma unroll
        for (int n = 0; n < 4; ++n)
          acc[m][n] = mfma16(af[m], bf[n], acc[m][n]);
    }
  }

#pragma unroll
  for (int m = 0; m < 4; ++m)
#pragma unroll
    for (int n = 0; n < 4; ++n) {
      int row0 = (int)gm + wr * 64 + m * 16 + g * 4;
      int col = (int)gn + wc * 64 + n * 16 + c16;
      float bz = bias[col];
      if (EPI == 1) {
        u16* C = (u16*)Cv;
        int bb = row0 >> 11, tt = row0 & 2047;
        union { u16 u[4]; uint2 v; } pk;
#pragma unroll
        for (int r = 0; r < 4; ++r) pk.u[r] = f2bf(acc[m][n][r] + bz);
        *reinterpret_cast<uint2*>(&C[((size_t)(bb * 2048 + col)) * 2048 + tt]) = pk.v;
      } else if (EPI == 2) {
        float* C = (float*)Cv;
#pragma unroll
        for (int r = 0; r < 4; ++r)
          C[(size_t)(row0 + r) * N + col] = acc[m][n][r] + bz;
      } else {  // EPI == 4: fused q|k
        u16* C = (u16*)Cv;
        if (row0 < 4096) {
#pragma unroll
          for (int r = 0; r < 4; ++r)
            C[(size_t)(row0 + r) * N + col] = f2bf(acc[m][n][r] + bz);
        } else {
          int t0 = row0 - 4096;
          int bb = t0 >> 11, tt = t0 & 2047;
          int str = col >> 10, hh = (col >> 6) & 15, dd = col & 63;
          u16* KT = C + 8388608;
          size_t base = (((size_t)(bb * 2 + str) * 16 + hh) * 2048 + tt) * (size_t)64 + dd;
#pragma unroll
          for (int r = 0; r < 4; ++r) KT[base + (size_t)r * 64] = f2bf(acc[m][n][r] + bz);
        }
      }
    }
}

// ---------------- differential flash attention + fused LN (32x32 swapped) ----
// grid 1024 (1D, XCD-swizzled), block 256 = 4 waves = 2 pairs.
// Pair p covers q-rows [xblk*64 + p*32, +32); wave stream s handles stream s+1.
// 64-key staged tiles, 2-barrier R8/R12-proven staging, COALESCED sources:
// K from kT (contiguous 8KB/stream/tile), V along t (64B/thread contiguous).
#define KROW 72   // K/V LDS row: 64 elems + 8 pad (144B)
#define YROW 72
__global__ __launch_bounds__(256, 3) void diffattn(
    const u16* __restrict__ q1q2, const u16* __restrict__ kT,
    const u16* __restrict__ vvT, const int* __restrict__ mask,
    const float* __restrict__ lq1, const float* __restrict__ lk1,
    const float* __restrict__ lq2, const float* __restrict__ lk2,
    const float* __restrict__ lnw, const float* __restrict__ lnb,
    u16* __restrict__ yout) {
  // Ks [128 rows = stream*64+key][KROW] = 9216 ; Vs [128 d-rows][KROW] = 9216
  __shared__ __align__(16) u16 smem[18432];
  u16* Ksm = smem;
  u16* Vsm = smem + 9216;
  u16* Ysm = smem;  // epilogue overlay

  int tid = threadIdx.x;
  int w = tid >> 6, l = tid & 63;
  int q = l & 31, hi = l >> 5;
  int pair = w >> 1, stream = w & 1;

  // XCD swizzle: same-(b,h) q-blocks land on one XCD -> K/V L2-local
  int id = blockIdx.x;            // 0..1023
  int j = id & 7, rest = id >> 3;
  int xblk = rest & 31, ygrp = rest >> 5;
  int bh = ygrp * 8 + j;
  int b = bh >> 4, h = bh & 15;
  int qr0 = xblk * 64 + pair * 32;

  // lambda
  float lm1 = lq1[h * 64 + l] * lk1[h * 64 + l];
  float lm2 = lq2[h * 64 + l] * lk2[h * 64 + l];
#pragma unroll
  for (int o = 32; o; o >>= 1) {
    lm1 += __shfl_xor(lm1, o);
    lm2 += __shfl_xor(lm2, o);
  }
  float lam = __expf(lm1) - __expf(lm2) + LAMBDA_INIT;

  int soff = stream * 1024;
  const u16* qrow = q1q2 + (size_t)(b * T_SEQ + qr0 + q) * 2048 + h * 64 + soff + hi * 8;
  short8 qf[4];
#pragma unroll
  for (int c = 0; c < 4; ++c) qf[c] = ld8(qrow + c * 16);

  // softmax in log2 domain; mask folds into scale (0 -> uniform softmax)
  float scale = (mask[b * T_SEQ + qr0 + q] == 0) ? 0.f : (SM_SCALE * LOG2E);

  float M = -INFINITY, Lp = 0.f;
  f32x16 acc[4] = {};

  // ---- coalesced staging (256 threads, 8 ld8/thread, all contiguous) ----
  // K: per stream, thread t covers 16 contiguous elems at offset t*16 of the
  //    64x64 kT tile (8KB contiguous per tile).
  int koff = tid * 16;                 // 0..4095
  int krw = koff >> 6, kcl = koff & 63;
  const u16* srcK0 = kT + (((size_t)(b * 2 + 0) * 16 + h) * 2048) * 64 + koff;
  const u16* srcK1 = kT + (((size_t)(b * 2 + 1) * 16 + h) * 2048) * 64 + koff;
  u16* dstK0 = &Ksm[krw * KROW + kcl];
  u16* dstK1 = &Ksm[(64 + krw) * KROW + kcl];
  // V: thread t covers 32 contiguous t-elems of d-row (t>>1) at col (t&1)*32.
  int vd0 = tid >> 1, tcol = (tid & 1) * 32;
  const u16* srcV = vvT + ((size_t)(b * 16 + h) * 128 + vd0) * 2048 + tcol;
  u16* dstV = &Vsm[vd0 * KROW + tcol];

  short8 kpa0, kpa1, kpb0, kpb1, vp0, vp1, vp2, vp3;
  kpa0 = ld8(srcK0); kpa1 = ld8(srcK0 + 8);
  kpb0 = ld8(srcK1); kpb1 = ld8(srcK1 + 8);
  vp0 = ld8(srcV); vp1 = ld8(srcV + 8); vp2 = ld8(srcV + 16); vp3 = ld8(srcV + 24);

  for (int kt = 0; kt < T_SEQ; kt += 64) {
    __syncthreads();  // previous tile's reads complete
    st8(dstK0, kpa0); st8(dstK0 + 8, kpa1);
    st8(dstK1, kpb0); st8(dstK1 + 8, kpb1);
    st8(dstV, vp0); st8(dstV + 8, vp1); st8(dstV + 16, vp2); st8(dstV + 24, vp3);
    __syncthreads();  // tile staged
    if (kt + 64 < T_SEQ) {  // prefetch next tile (consumed NEXT iter)
      size_t ko = (size_t)(kt + 64) * 64;
      kpa0 = ld8(srcK0 + ko); kpa1 = ld8(srcK0 + ko + 8);
      kpb0 = ld8(srcK1 + ko); kpb1 = ld8(srcK1 + ko + 8);
      const u16* nv = srcV + kt + 64;
      vp0 = ld8(nv); vp1 = ld8(nv + 8); vp2 = ld8(nv + 16); vp3 = ld8(nv + 24);
    }

#pragma unroll
    for (int st = 0; st < 2; ++st) {
      const u16* kbase = &Ksm[(stream * 64 + st * 32 + q) * KROW + hi * 8];
      short8 kf[4];
#pragma unroll
      for (int c = 0; c < 4; ++c) kf[c] = ld8(kbase + c * 16);

      f32x16 s = {};
#pragma unroll
      for (int c = 0; c < 4; ++c) s = mfma32(kf[c], qf[c], s);

      // tile max: max3-fusable tree + cross-half
      float m0 = fmaxf(fmaxf(s[0], s[1]), s[2]);
      float m1 = fmaxf(fmaxf(s[3], s[4]), s[5]);
      float m2 = fmaxf(fmaxf(s[6], s[7]), s[8]);
      float m3 = fmaxf(fmaxf(s[9], s[10]), s[11]);
      float m4 = fmaxf(fmaxf(s[12], s[13]), s[14]);
      float ma = fmaxf(fmaxf(m0, m1), m2);
      float mb = fmaxf(fmaxf(m3, m4), s[15]);
      float rm = fmaxf(ma, mb);
      rm = fmaxf(rm, __shfl_xor(rm, 32));
      float tm = rm * scale;

      // defer-max (log2 units: 11.5 ~ e^8); M synced across halves
      if (!__all(tm - M <= 11.5f)) {
        float Mn = fmaxf(M, tm);
        float a = exp2f(M - Mn);
        Lp *= a;
#pragma unroll
        for (int d = 0; d < 4; ++d) acc[d] *= a;
        M = Mn;
      }

      // p = exp2(s*scale - M); lane-local partial sum (combined once at end)
      float p[16];
#pragma unroll
      for (int r = 0; r < 16; ++r) p[r] = exp2f(__builtin_fmaf(s[r], scale, -M));
      float s8[8], s4[4];
#pragma unroll
      for (int i = 0; i < 8; ++i) s8[i] = p[i] + p[i + 8];
#pragma unroll
      for (int i = 0; i < 4; ++i) s4[i] = s8[i] + s8[i + 4];
      Lp += (s4[0] + s4[1]) + (s4[2] + s4[3]);

      // P^T B-frags in-register
      uint32_t a1 = cvtpk(p[0], p[1]), a2 = cvtpk(p[2], p[3]);
      uint32_t b1 = cvtpk(p[4], p[5]), b2 = cvtpk(p[6], p[7]);
      uint32_t c1 = cvtpk(p[8], p[9]), c2 = cvtpk(p[10], p[11]);
      uint32_t d1 = cvtpk(p[12], p[13]), d2 = cvtpk(p[14], p[15]);
      uint32_t sa1 = (uint32_t)__shfl_xor((int)a1, 32), sa2 = (uint32_t)__shfl_xor((int)a2, 32);
      uint32_t sb1 = (uint32_t)__shfl_xor((int)b1, 32), sb2 = (uint32_t)__shfl_xor((int)b2, 32);
      uint32_t sc1 = (uint32_t)__shfl_xor((int)c1, 32), sc2 = (uint32_t)__shfl_xor((int)c2, 32);
      uint32_t sd1 = (uint32_t)__shfl_xor((int)d1, 32), sd2 = (uint32_t)__shfl_xor((int)d2, 32);
      union { uint32_t u[4]; short8 s8v; } pu0, pu1;
      pu0.u[0] = hi ? sb1 : a1;  pu0.u[1] = hi ? sb2 : a2;
      pu0.u[2] = hi ? b1 : sa1;  pu0.u[3] = hi ? b2 : sa2;
      pu1.u[0] = hi ? sd1 : c1;  pu1.u[1] = hi ? sd2 : c2;
      pu1.u[2] = hi ? d1 : sc1;  pu1.u[3] = hi ? d2 : sc2;
      short8 pf0 = pu0.s8v, pf1 = pu1.s8v;

#pragma unroll
      for (int d = 0; d < 4; ++d) {
        const u16* vb0 = &Vsm[(d * 32 + q) * KROW + st * 32 + hi * 8];
        short8 vf0 = ld8(vb0);
        short8 vf1 = ld8(vb0 + 16);
        acc[d] = mfma32(vf0, pf0, acc[d]);
        acc[d] = mfma32(vf1, pf1, acc[d]);
      }
    }
  }

  float L = Lp + __shfl_xor(Lp, 32);
  float inv = 1.f / L;
  __syncthreads();  // staging dead -> Ysm overlay safe
  if (stream == 1) {
    u16* yrow = &Ysm[(pair * 64 + l) * YROW];
#pragma unroll
    for (int d = 0; d < 4; ++d) {
      union { uint32_t u[8]; short8 v[2]; } pk;
#pragma unroll
      for (int i = 0; i < 8; ++i)
        pk.u[i] = cvtpk(acc[d][2 * i] * inv, acc[d][2 * i + 1] * inv);
      st8(yrow + d * 16, pk.v[0]);
      st8(yrow + d * 16 + 8, pk.v[1]);
    }
  }
  __syncthreads();
  if (stream == 0) {
    const u16* yrow = &Ysm[(pair * 64 + l) * YROW];
    float y[4][16];
#pragma unroll
    for (int d = 0; d < 4; ++d) {
      short8 y2a = ld8(yrow + d * 16);
      short8 y2b = ld8(yrow + d * 16 + 8);
#pragma unroll
      for (int i = 0; i < 8; ++i) {
        y[d][i] = acc[d][i] * inv - lam * b2f((u16)y2a[i]);
        y[d][8 + i] = acc[d][8 + i] * inv - lam * b2f((u16)y2b[i]);
      }
    }
    float sm = 0.f;
#pragma unroll
    for (int d = 0; d < 4; ++d)
#pragma unroll
      for (int r = 0; r < 16; ++r) sm += y[d][r];
    sm += __shfl_xor(sm, 32);
    float u = sm * (1.f / 128.f);
    float var = 0.f;
#pragma unroll
    for (int d = 0; d < 4; ++d)
#pragma unroll
      for (int r = 0; r < 16; ++r) { float dd = y[d][r] - u; var += dd * dd; }
    var += __shfl_xor(var, 32);
    float rstd = rsqrtf(var * (1.f / 128.f) + 1e-12f);

    size_t orow = (size_t)(b * T_SEQ + qr0 + q) * 2048 + h * 128;
#pragma unroll
    for (int d = 0; d < 4; ++d)
#pragma unroll
      for (int rr = 0; rr < 4; ++rr) {
        int base = d * 32 + 8 * rr + 4 * hi;
        union { u16 u[4]; uint2 v; } o;
#pragma unroll
        for (int i = 0; i < 4; ++i) {
          float yv = (lnw[base + i] * ((y[d][rr * 4 + i] - u) * rstd) + lnb[base + i]) *
                     ONE_MINUS_LI;
          o.u[i] = f2bf(yv);
        }
        *reinterpret_cast<uint2*>(&yout[orow + base]) = o.v;
      }
  }
}

// ---------------- host ----------------
extern "C" void kernel_launch(void* const* d_in, const int* in_sizes, int n_in,
                              void* d_out, int out_size, void* d_ws, size_t ws_size,
                              hipStream_t stream) {
  (void)in_sizes; (void)n_in; (void)out_size; (void)ws_size;
  const float* q   = (const float*)d_in[0];
  const float* k   = (const float*)d_in[1];
  const float* v   = (const float*)d_in[2];
  const int* maskp = (const int*)d_in[3];
  const float* Wq1 = (const float*)d_in[4];
  const float* bq1 = (const float*)d_in[5];
  const float* Wq2 = (const float*)d_in[6];
  const float* bq2 = (const float*)d_in[7];
  const float* Wk1 = (const float*)d_in[8];
  const float* bk1 = (const float*)d_in[9];
  const float* Wk2 = (const float*)d_in[10];
  const float* bk2 = (const float*)d_in[11];
  const float* Wv  = (const float*)d_in[12];
  const float* bv  = (const float*)d_in[13];
  const float* Wc  = (const float*)d_in[14];
  const float* bc  = (const float*)d_in[15];
  const float* lnw = (const float*)d_in[16];
  const float* lnb = (const float*)d_in[17];
  const float* lq1 = (const float*)d_in[18];
  const float* lk1 = (const float*)d_in[19];
  const float* lq2 = (const float*)d_in[20];
  const float* lk2 = (const float*)d_in[21];

  char* ws = (char*)d_ws;
  u16* qb     = (u16*)(ws + 0);          // rows 0..4095 ; kb continues at 4096
  u16* kb     = (u16*)(ws + 8388608);
  u16* vb     = (u16*)(ws + 16777216);
  u16* Wq12T  = (u16*)(ws + 25165824);   // Wk12T contiguous after
  u16* Wk12T  = (u16*)(ws + 29360128);
  u16* WvT    = (u16*)(ws + 33554432);
  u16* WcT    = (u16*)(ws + 37748736);
  float* biasq = (float*)(ws + 41943040);  // biask contiguous after
  float* biask = (float*)(ws + 41951232);
  u16* q1q2   = (u16*)(ws + 41959424);   // kT contiguous after (+8388608 elems)
  u16* kT     = (u16*)(ws + 58736640);
  u16* vvT    = (u16*)(ws + 75513856);
  u16* yb     = (u16*)(ws + 0);  // alias qb+kb (16MB; both dead before attention)

  const int NELEM = 2 * T_SEQ * 1024;  // 4,194,304

  cvt_bf16<<<4096, 256, 0, stream>>>(q, qb, NELEM);
  cvt_bf16<<<4096, 256, 0, stream>>>(k, kb, NELEM);
  cvt_bf16<<<4096, 256, 0, stream>>>(v, vb, NELEM);

  tcvt<<<dim3(32, 32), 256, 0, stream>>>(Wq1, Wq12T, 1024, 1024, 0);
  tcvt<<<dim3(32, 32), 256, 0, stream>>>(Wq2, Wq12T, 1024, 1024, 1024);
  tcvt<<<dim3(32, 32), 256, 0, stream>>>(Wk1, Wk12T, 1024, 1024, 0);
  tcvt<<<dim3(32, 32), 256, 0, stream>>>(Wk2, Wk12T, 1024, 1024, 1024);
  tcvt<<<dim3(64, 32), 256, 0, stream>>>(Wv, WvT, 1024, 2048, 0);
  tcvt<<<dim3(32, 64), 256, 0, stream>>>(Wc, WcT, 2048, 1024, 0);

  bias_concat<<<8, 256, 0, stream>>>(bq1, bq2, biasq);
  bias_concat<<<8, 256, 0, stream>>>(bk1, bk2, biask);

  // fused q-proj + k-proj: M=8192; q-half -> q1q2 (bf16 MN), k-half -> kT layout
  gemm_bt<4, true><<<dim3(16, 64), 256, 0, stream>>>(qb, Wq12T, biasq, q1q2,
                                                     8192, 2048, 1024);
  gemm_bt<1, false><<<dim3(16, 32), 256, 0, stream>>>(vb, WvT, bv, vvT, 4096, 2048, 1024);

  diffattn<<<1024, 256, 0, stream>>>(q1q2, kT, vvT, maskp,
                                     lq1, lk1, lq2, lk2, lnw, lnb, yb);

  gemm_bt<2, false><<<dim3(8, 32), 256, 0, stream>>>(yb, WcT, bc, d_out, 4096, 1024, 2048);
}